// Round 7
// baseline (269.810 us; speedup 1.0000x reference)
//
#include <hip/hip_runtime.h>
#include <hip/hip_fp16.h>
#include <cstdint>
#include <cstddef>
#include <math.h>

#define B_ 2
#define T_ 2048
#define D_ 1024
#define M_ (B_*T_)

// column layout of P (= row layout of W concat), all offsets multiples of 8
#define QO0 0
#define KO0 128
#define WO0 160
#define QO1 168
#define KO1 680
#define WO1 744
#define QO2 752
#define KO2 2800
#define WO2 2928
#define SELO 2944
#define LDN 3072

typedef float f32x16 __attribute__((ext_vector_type(16)));
typedef short bf16x8 __attribute__((ext_vector_type(8)));
typedef unsigned short u16;

__device__ __forceinline__ u16 f2bf(float f) {
    unsigned int u = __float_as_uint(f);
    unsigned int r = (u + 0x7fffu + ((u >> 16) & 1u)) >> 16;   // RNE
    return (u16)r;
}
__device__ __forceinline__ float bf2f(u16 b) {
    return __uint_as_float(((unsigned int)b) << 16);
}

// async global->LDS, 16B per lane, dest = wave-uniform base + lane*16
__device__ __forceinline__ void gload16(const void* g, void* l) {
    __builtin_amdgcn_global_load_lds(
        (const __attribute__((address_space(1))) unsigned int*)g,
        (__attribute__((address_space(3))) unsigned int*)l,
        16, 0, 0);
}

// Bank-conflict-free 16row x 32col u16 plane-slice staging with XOR swizzle.
// LDS slot s of row r holds logical 8-u16 chunk s ^ tkey(r), tkey(r) = (r&3)^((r>>2)&3).
__device__ __forceinline__ void stage_plane(const u16* src_base, int row_stride, int k0,
                                            int rg, int lane, u16* dst) {
    int rl  = lane >> 2;
    int row = rg * 16 + rl;
    int q   = (lane & 3) ^ (rl & 3) ^ ((rl >> 2) & 3);
    const u16* s = src_base + (size_t)row * row_stride + k0 + q * 8;
    gload16(s, dst + rg * 512);
}

// ---------------- merged: stats1 partial sums + x->bf16  |  weight concat ----------------
__global__ void prep(const float* __restrict__ x, float* __restrict__ part,
                     float* __restrict__ part2, u16* __restrict__ Xh,
                     const float* __restrict__ qw0, const float* __restrict__ kw0,
                     const float* __restrict__ ww0, const float* __restrict__ qw1,
                     const float* __restrict__ kw1, const float* __restrict__ ww1,
                     const float* __restrict__ qw2, const float* __restrict__ kw2,
                     const float* __restrict__ ww2, const float* __restrict__ w1s,
                     u16* __restrict__ Wh) {
    int bid = blockIdx.x;
    if (bid < 256) {
        int d4 = threadIdx.x * 4;
        int tc = bid & 127;
        int b  = bid >> 7;
        size_t base = (size_t)b * T_ * D_ + (size_t)tc * 16 * D_ + d4;
        float4 s = make_float4(0.f, 0.f, 0.f, 0.f);
        float4 s2 = make_float4(0.f, 0.f, 0.f, 0.f);
#pragma unroll
        for (int t = 0; t < 16; ++t) {
            float4 v = *(const float4*)(x + base + (size_t)t * D_);
            s.x += v.x; s.y += v.y; s.z += v.z; s.w += v.w;
            s2.x += v.x * v.x; s2.y += v.y * v.y; s2.z += v.z * v.z; s2.w += v.w * v.w;
            ushort4 h;
            h.x = f2bf(v.x); h.y = f2bf(v.y); h.z = f2bf(v.z); h.w = f2bf(v.w);
            *(ushort4*)(Xh + base + (size_t)t * D_) = h;
        }
        *(float4*)(part  + (size_t)(b * 128 + tc) * D_ + d4) = s;
        *(float4*)(part2 + (size_t)(b * 128 + tc) * D_ + d4) = s2;
    } else {
        int row = bid - 256;
        int col = threadIdx.x * 4;
        const float* src = nullptr;
        if      (row < 128)  src = qw0 + (size_t)row * D_;
        else if (row < 160)  src = kw0 + (size_t)(row - 128) * D_;
        else if (row < 164)  src = ww0 + (size_t)(row - 160) * D_;
        else if (row < 168)  src = nullptr;
        else if (row < 680)  src = qw1 + (size_t)(row - 168) * D_;
        else if (row < 744)  src = kw1 + (size_t)(row - 680) * D_;
        else if (row < 752)  src = ww1 + (size_t)(row - 744) * D_;
        else if (row < 2800) src = qw2 + (size_t)(row - 752) * D_;
        else if (row < 2928) src = kw2 + (size_t)(row - 2800) * D_;
        else if (row < 2944) src = ww2 + (size_t)(row - 2928) * D_;
        else if (row < 3008) src = w1s + (size_t)(row - 2944) * D_;
        float4 v = src ? *(const float4*)(src + col) : make_float4(0.f, 0.f, 0.f, 0.f);
        ushort4 h;
        h.x = f2bf(v.x); h.y = f2bf(v.y); h.z = f2bf(v.z); h.w = f2bf(v.w);
        *(ushort4*)&Wh[(size_t)row * D_ + col] = h;
    }
}

// ---------------- pass 2: finalize mean+std, fold msd & s1 ----------------
__global__ void stats2(const float* __restrict__ part, const float* __restrict__ part2,
                       const float* __restrict__ w1,
                       float* __restrict__ msd, float* __restrict__ s1) {
    __shared__ float msL[1024];
    __shared__ float ps[64][17];
    __shared__ float pw[64][17];
    int b = blockIdx.x, tid = threadIdx.x;
    float s = 0.f, s2 = 0.f;
#pragma unroll 8
    for (int i = 0; i < 128; ++i) {
        s  += part [(b * 128 + i) * D_ + tid];
        s2 += part2[(b * 128 + i) * D_ + tid];
    }
    float mean = s / (float)T_;
    float var  = (s2 - (float)T_ * mean * mean) / (float)(T_ - 1);
    msL[tid] = mean + sqrtf(fmaxf(var, 0.f));
    __syncthreads();
    int j = tid >> 4, cc = tid & 15;
    float am = 0.f, aw = 0.f;
    const float* wr = w1 + (size_t)j * D_ + cc * 64;
    const float* mr = msL + cc * 64;
    for (int dd = 0; dd < 64; ++dd) { float w = wr[dd]; am += mr[dd] * w; aw += w; }
    ps[j][cc] = am; pw[j][cc] = aw;
    __syncthreads();
    if (tid < 64) {
        float sm = 0.f, sw = 0.f;
        for (int i = 0; i < 16; ++i) { sm += ps[tid][i]; sw += pw[tid][i]; }
        msd[b * 64 + tid] = sm;
        if (b == 0) s1[tid] = sw;
    }
}

// ---------------- projection GEMM, m97-style: BK=64 single-buffered ----------------
__global__ __launch_bounds__(256, 3) void proj_gemm(
    const u16* __restrict__ Xh, const u16* __restrict__ Wh, u16* __restrict__ Ph) {
    __shared__ u16 As[8192], Bs[8192];   // 128 rows x 64 cols (2 planes of 32)
    int tid = threadIdx.x;
    int wave = tid >> 6, lane = tid & 63;
    int bm = blockIdx.x * 128, bn = blockIdx.y * 128;
    int wt = wave >> 1, wn = wave & 1;
    int fm = lane & 31, hv = lane >> 5;
    int tkey = (fm & 3) ^ ((fm >> 2) & 3);
    f32x16 acc[2][2];
#pragma unroll
    for (int i = 0; i < 2; ++i)
#pragma unroll
        for (int j = 0; j < 2; ++j)
#pragma unroll
            for (int r = 0; r < 16; ++r) acc[i][j][r] = 0.f;

    const u16* xh = Xh + (size_t)bm * D_;
    const u16* wh = Wh + (size_t)bn * D_;

    for (int kc = 0; kc < 16; ++kc) {
        int k0 = kc * 64;
#pragma unroll
        for (int i = 0; i < 8; ++i) {
            int j = wave * 8 + i;
            int mat = j >> 4;
            int pl  = (j >> 3) & 1;
            int rg  = j & 7;
            stage_plane(mat ? wh : xh, D_, k0 + pl * 32, rg, lane,
                        (mat ? Bs : As) + pl * 4096);
        }
        __syncthreads();
#pragma unroll
        for (int ks = 0; ks < 4; ++ks) {
            int pl = ks >> 1;
            int slot8 = (((ks & 1) * 2 + hv) ^ tkey) * 8;
            bf16x8 a_h[2], b_h[2];
#pragma unroll
            for (int t = 0; t < 2; ++t) {
                a_h[t] = *(const bf16x8*)&As[pl * 4096 + (wt * 64 + t * 32 + fm) * 32 + slot8];
                b_h[t] = *(const bf16x8*)&Bs[pl * 4096 + (wn * 64 + t * 32 + fm) * 32 + slot8];
            }
#pragma unroll
            for (int ti = 0; ti < 2; ++ti)
#pragma unroll
                for (int tj = 0; tj < 2; ++tj)
                    acc[ti][tj] = __builtin_amdgcn_mfma_f32_32x32x16_bf16(a_h[ti], b_h[tj], acc[ti][tj], 0, 0, 0);
        }
        __syncthreads();
    }
#pragma unroll
    for (int ti = 0; ti < 2; ++ti)
#pragma unroll
        for (int tj = 0; tj < 2; ++tj)
#pragma unroll
            for (int r = 0; r < 16; ++r) {
                int row = bm + wt * 64 + ti * 32 + (r & 3) + 8 * (r >> 2) + 4 * hv;
                int col = bn + wn * 64 + tj * 32 + fm;
                Ph[(size_t)row * LDN + col] = f2bf(acc[ti][tj][r]);
            }
}

// ---------------- selector layers 2-3 + softmax + WP=w*prob (f16) ----------
__global__ void selector2(const u16* __restrict__ Ph,
                          const float* __restrict__ msd, const float* __restrict__ s1,
                          const float* __restrict__ b1, const float* __restrict__ w2,
                          const float* __restrict__ b2, const float* __restrict__ w3,
                          const float* __restrict__ b3, __half* __restrict__ WP) {
    __shared__ float h1s[4][64];
    __shared__ float h2s[4][64];
    __shared__ float lg[4][3];
    int tid = threadIdx.x;
    int slot = tid >> 6, j = tid & 63;
    int bt = blockIdx.x * 4 + slot;
    int b = bt >> 11, t = bt & 2047;
    size_t pidx = (size_t)bt * LDN + SELO + j;
    float v = bf2f(Ph[pidx])
            + msd[b * 64 + j] + 0.1f * ((float)t / (float)T_) * s1[j] + b1[j];
    h1s[slot][j] = fmaxf(v, 0.f);
    __syncthreads();
    float a2 = b2[j];
    {
        const float4* w2v = (const float4*)(w2 + (size_t)j * 64);
        const float4* h1v = (const float4*)h1s[slot];
#pragma unroll
        for (int d = 0; d < 16; ++d) {
            float4 wv = w2v[d], hv4 = h1v[d];
            a2 = fmaf(hv4.x, wv.x, a2);
            a2 = fmaf(hv4.y, wv.y, a2);
            a2 = fmaf(hv4.z, wv.z, a2);
            a2 = fmaf(hv4.w, wv.w, a2);
        }
    }
    h2s[slot][j] = fmaxf(a2, 0.f);
    __syncthreads();
    if (j < 3) {
        float a3 = b3[j];
        const float4* w3v = (const float4*)(w3 + (size_t)j * 64);
        const float4* h2v = (const float4*)h2s[slot];
#pragma unroll
        for (int d = 0; d < 16; ++d) {
            float4 wv = w3v[d], hv4 = h2v[d];
            a3 = fmaf(hv4.x, wv.x, a3);
            a3 = fmaf(hv4.y, wv.y, a3);
            a3 = fmaf(hv4.z, wv.z, a3);
            a3 = fmaf(hv4.w, wv.w, a3);
        }
        lg[slot][j] = a3;
    }
    __syncthreads();
    if (j < 28) {
        float m = fmaxf(lg[slot][0], fmaxf(lg[slot][1], lg[slot][2]));
        float e0 = expf(lg[slot][0] - m), e1 = expf(lg[slot][1] - m), e2 = expf(lg[slot][2] - m);
        float inv = 1.f / (e0 + e1 + e2);
        int wcol = (j < 4) ? (WO0 + j) : ((j < 12) ? (WO1 + j - 4) : (WO2 + j - 12));
        float p = ((j < 4) ? e0 : ((j < 12) ? e1 : e2)) * inv;
        float w = bf2f(Ph[(size_t)bt * LDN + wcol]);
        WP[(size_t)(b * 28 + j) * T_ + t] = __float2half(w * p);
    }
}

__device__ __forceinline__ int qcol_of(int c) {
    if (c < 2)  return QO0 + c * 64;
    if (c < 10) return QO1 + (c - 2) * 64;
    return QO2 + (c - 10) * 64;
}

// ---------------- fused relu-attention score kernel ----------------
// block 128x128, 4 waves 64x64. K ENTIRELY IN REGISTERS (28 bf16x8, loaded
// once in prologue — main loop reads only Q from LDS: 2 b128/ks-step).
// 4-deep Q ring, barrier pair per 2 phases (21 epochs, was 42).
__global__ __launch_bounds__(256, 2) void score_kernel(
    const u16* __restrict__ Ph, const __half* __restrict__ WP, float* __restrict__ out) {
    __shared__ u16 Qr[4][8192];    // 4-deep Q ring (each buf: 2 planes x [128][32])
    __shared__ __half wpL[3584];   // [28][128]
    u16* QrF = &Qr[0][0];
    int tid = threadIdx.x;
    int wave = tid >> 6, lane = tid & 63;
    int wt = wave >> 1, wn = wave & 1;
    int fm = lane & 31, hv = lane >> 5;
    int tkey = (fm & 3) ^ ((fm >> 2) & 3);

    // XCD-aware swizzle: blocks sharing a Q-tile land on one XCD
    int n = blockIdx.z * 256 + blockIdx.y * 16 + blockIdx.x;
    int p = (n & 7) * 4 + (n >> 7);
    int xb = (n >> 3) & 15;
    int b = p >> 4, yb = p & 15;
    int t0 = yb * 128, s0 = xb * 128;

    const u16* Pq = Ph + (size_t)(b * T_ + t0) * LDN;
    const u16* Pk = Ph + (size_t)(b * T_ + s0) * LDN;
    int rl = lane >> 2;
    int q8 = ((lane & 3) ^ (rl & 3) ^ ((rl >> 2) & 3)) * 8;
    const u16* PqL = Pq + (size_t)rl * LDN + q8;
    const u16* PkL = Pk + (size_t)rl * LDN + q8;

    auto stageQ = [&](u16* buf, int qcol) {
#pragma unroll
        for (int i = 0; i < 4; ++i) {
            int j = (wave << 2) + i;
            int pl = j >> 3, rg = j & 7;
            gload16(PqL + (size_t)(rg * 16) * LDN + pl * 32 + qcol,
                    buf + pl * 4096 + rg * 512);
        }
    };

    // ---- prologue: stage all 7 K planes into Qr (areas: p0..p2 -> Qr[2..3],
    // p3..p6 -> Qr[0..1]); wp slice; then read K to regs; then stage Q0-3.
#pragma unroll
    for (int i = 0; i < 14; ++i) {
        int j = i * 4 + wave;                  // 0..55
        int rg, col, offW;
        if (j < 24) {
            int pl = j >> 3; rg = j & 7;
            col = (pl == 0) ? KO0 : ((pl == 1) ? KO1 : KO1 + 32);
            offW = 16384 + pl * 4096;          // planes 0-2 in Qr[2],Qr[3] front half
        } else {
            int jj = j - 24; int pl = jj >> 3; rg = jj & 7;
            col = KO2 + pl * 32;
            offW = pl * 4096;                  // planes 3-6 in Qr[0],Qr[1]
        }
        gload16(PkL + (size_t)(rg * 16) * LDN + col, QrF + offW + rg * 512);
    }
#pragma unroll
    for (int i = 0; i < 2; ++i) {
        int j = i * 4 + wave;
        if (j < 7) {
            const __half* src = WP + (size_t)(b * 28 + j * 4 + (lane >> 4)) * T_ + t0 + (lane & 15) * 8;
            gload16(src, (u16*)wpL + j * 512);
        }
    }
    __syncthreads();                           // drains vmcnt: all K planes + wp in LDS

    // read 28 K fragments into registers (all indices compile-time)
    int slotE = (hv ^ tkey) * 8;
    int slotO = (((2 + hv)) ^ tkey) * 8;
    int rowK0 = (wn * 64 + fm) * 32;
    int rowK1 = rowK0 + 32 * 32;
    bf16x8 krE[7][2], krO[7][2];
#pragma unroll
    for (int pp = 0; pp < 7; ++pp) {
        int base = (pp < 3) ? (16384 + pp * 4096) : ((pp - 3) * 4096);
        krE[pp][0] = *(const bf16x8*)(QrF + base + rowK0 + slotE);
        krE[pp][1] = *(const bf16x8*)(QrF + base + rowK1 + slotE);
        krO[pp][0] = *(const bf16x8*)(QrF + base + rowK0 + slotO);
        krO[pp][1] = *(const bf16x8*)(QrF + base + rowK1 + slotO);
    }
    asm volatile("s_waitcnt lgkmcnt(0)" ::: "memory");
    __syncthreads();                           // all waves' K reads done -> Qr reusable

    // deep-prefetch Q phases 0..3 into ring bufs 0..3
    stageQ(QrF,         qcol_of(0));
    stageQ(QrF +  8192, qcol_of(1));
    stageQ(QrF + 16384, qcol_of(2));
    stageQ(QrF + 24576, qcol_of(3));
    __syncthreads();                           // drains vmcnt(0)

    int qoE0 = (wt * 64 + fm) * 32 + slotE;
    int qoE1 = qoE0 + 32 * 32;
    int qoO0 = (wt * 64 + fm) * 32 + slotO;
    int qoO1 = qoO0 + 32 * 32;

    f32x16 outacc[2][2], dots[2][2], Z16;
#pragma unroll
    for (int r = 0; r < 16; ++r) Z16[r] = 0.f;
#pragma unroll
    for (int i = 0; i < 2; ++i)
#pragma unroll
        for (int j = 0; j < 2; ++j)
#pragma unroll
            for (int r = 0; r < 16; ++r) { outacc[i][j][r] = 0.f; dots[i][j][r] = 0.f; }

    // relu-weight epilogue for head g (dots -> outacc)
    auto epi = [&](int g) {
#pragma unroll
        for (int ti = 0; ti < 2; ++ti) {
            int rowbase = wt * 64 + ti * 32 + 4 * hv;
#pragma unroll
            for (int rq = 0; rq < 4; ++rq) {
                __half2 wpq[2];
                *(short4*)wpq = *(const short4*)&wpL[g * 128 + rowbase + rq * 8];
                float2 f01 = __half22float2(wpq[0]);
                float2 f23 = __half22float2(wpq[1]);
                float wv[4] = {f01.x, f01.y, f23.x, f23.y};
#pragma unroll
                for (int tj = 0; tj < 2; ++tj)
#pragma unroll
                    for (int r2 = 0; r2 < 4; ++r2) {
                        int r = rq * 4 + r2;
                        outacc[ti][tj][r] += fmaxf(dots[ti][tj][r], 0.f) * wv[r2];
                    }
            }
        }
    };

    auto MFMA4 = [&](bf16x8 q0, bf16x8 q1, bf16x8 k0, bf16x8 k1, bool zero) {
        __builtin_amdgcn_s_setprio(1);
        dots[0][0] = __builtin_amdgcn_mfma_f32_32x32x16_bf16(q0, k0, zero ? Z16 : dots[0][0], 0, 0, 0);
        dots[0][1] = __builtin_amdgcn_mfma_f32_32x32x16_bf16(q0, k1, zero ? Z16 : dots[0][1], 0, 0, 0);
        dots[1][0] = __builtin_amdgcn_mfma_f32_32x32x16_bf16(q1, k0, zero ? Z16 : dots[1][0], 0, 0, 0);
        dots[1][1] = __builtin_amdgcn_mfma_f32_32x32x16_bf16(q1, k1, zero ? Z16 : dots[1][1], 0, 0, 0);
        __builtin_amdgcn_s_setprio(0);
    };

    // one 64-col phase; K fragments passed by value (literal reg indices at
    // call sites). Q reads software-pipelined one ks-step ahead.
    auto computePhase = [&](const u16* qb,
                            bf16x8 kEa0, bf16x8 kEa1, bf16x8 kOa0, bf16x8 kOa1,
                            bf16x8 kEb0, bf16x8 kEb1, bf16x8 kOb0, bf16x8 kOb1,
                            bool z0, bool midBreak, int gMid, bool hasEnd, int gEnd) {
        bf16x8 q0 = *(const bf16x8*)(qb + qoE0);
        bf16x8 q1 = *(const bf16x8*)(qb + qoE1);
        bf16x8 n0, n1;
        // ks=0 (plane0,E)
        n0 = *(const bf16x8*)(qb + qoO0);
        n1 = *(const bf16x8*)(qb + qoO1);
        MFMA4(q0, q1, kEa0, kEa1, z0);
        q0 = n0; q1 = n1;
        // ks=1 (plane0,O)
        n0 = *(const bf16x8*)(qb + 4096 + qoE0);
        n1 = *(const bf16x8*)(qb + 4096 + qoE1);
        MFMA4(q0, q1, kOa0, kOa1, false);
        if (midBreak) epi(gMid);
        q0 = n0; q1 = n1;
        // ks=2 (plane1,E)
        n0 = *(const bf16x8*)(qb + 4096 + qoO0);
        n1 = *(const bf16x8*)(qb + 4096 + qoO1);
        MFMA4(q0, q1, kEb0, kEb1, midBreak);
        q0 = n0; q1 = n1;
        // ks=3 (plane1,O)
        MFMA4(q0, q1, kOb0, kOb1, false);
        if (hasEnd) epi(gEnd);
    };

    // ---- epoch 0: phases 0,1 (cfg0, K plane 0 both halves), bufs 0,1; pre-staged
    computePhase(QrF,        krE[0][0], krE[0][1], krO[0][0], krO[0][1],
                             krE[0][0], krE[0][1], krO[0][0], krO[0][1],
                 true, true, 0, true, 1);
    computePhase(QrF + 8192, krE[0][0], krE[0][1], krO[0][0], krO[0][1],
                             krE[0][0], krE[0][1], krO[0][0], krO[0][1],
                 true, true, 2, true, 3);
    asm volatile("s_waitcnt lgkmcnt(0)" ::: "memory");
    __builtin_amdgcn_sched_barrier(0);
    __builtin_amdgcn_s_barrier();              // B: epoch-0 reads done everywhere

    // ---- epochs 1..4: cfg1 (K planes 1,2), phases 2e,2e+1
    for (int e = 1; e <= 4; ++e) {
        int c0 = 2 * e;
        stageQ(QrF + ((c0 + 2) & 3) * 8192, qcol_of(c0 + 2));
        stageQ(QrF + ((c0 + 3) & 3) * 8192, qcol_of(c0 + 3));
        asm volatile("s_waitcnt vmcnt(8)" ::: "memory");
        __builtin_amdgcn_s_barrier();          // A: phases c0,c0+1 staged & visible
        __builtin_amdgcn_sched_barrier(0);
        computePhase(QrF + (c0 & 3) * 8192,
                     krE[1][0], krE[1][1], krO[1][0], krO[1][1],
                     krE[2][0], krE[2][1], krO[2][0], krO[2][1],
                     true, false, -1, true, c0 + 2);
        computePhase(QrF + ((c0 + 1) & 3) * 8192,
                     krE[1][0], krE[1][1], krO[1][0], krO[1][1],
                     krE[2][0], krE[2][1], krO[2][0], krO[2][1],
                     true, false, -1, true, c0 + 3);
        asm volatile("s_waitcnt lgkmcnt(0)" ::: "memory");
        __builtin_amdgcn_sched_barrier(0);
        __builtin_amdgcn_s_barrier();          // B
    }

    // ---- epochs 5..20: cfg2 (K planes 3,4 then 5,6), phase pairs
    for (int e = 5; e <= 20; ++e) {
        int c0 = 2 * e;
        if (e < 20) {
            stageQ(QrF + ((c0 + 2) & 3) * 8192, qcol_of(c0 + 2));
            stageQ(QrF + ((c0 + 3) & 3) * 8192, qcol_of(c0 + 3));
            asm volatile("s_waitcnt vmcnt(8)" ::: "memory");
        } else {
            asm volatile("s_waitcnt vmcnt(0)" ::: "memory");
        }
        __builtin_amdgcn_s_barrier();          // A
        __builtin_amdgcn_sched_barrier(0);
        computePhase(QrF + (c0 & 3) * 8192,
                     krE[3][0], krE[3][1], krO[3][0], krO[3][1],
                     krE[4][0], krE[4][1], krO[4][0], krO[4][1],
                     true, false, -1, false, -1);
        computePhase(QrF + ((c0 + 1) & 3) * 8192,
                     krE[5][0], krE[5][1], krO[5][0], krO[5][1],
                     krE[6][0], krE[6][1], krO[6][0], krO[6][1],
                     false, false, -1, true, 12 + (e - 5));
        asm volatile("s_waitcnt lgkmcnt(0)" ::: "memory");
        __builtin_amdgcn_sched_barrier(0);
        __builtin_amdgcn_s_barrier();          // B
    }

#pragma unroll
    for (int ti = 0; ti < 2; ++ti)
#pragma unroll
        for (int tj = 0; tj < 2; ++tj)
#pragma unroll
            for (int r = 0; r < 16; ++r) {
                int trow = wt * 64 + ti * 32 + (r & 3) + 8 * (r >> 2) + 4 * hv;
                int scol = wn * 64 + tj * 32 + fm;
                __builtin_nontemporal_store(outacc[ti][tj][r],
                    &out[(size_t)(b * T_ + t0 + trow) * T_ + (s0 + scol)]);
            }
}

extern "C" void kernel_launch(void* const* d_in, const int* in_sizes, int n_in,
                              void* d_out, int out_size, void* d_ws, size_t ws_size,
                              hipStream_t stream) {
    const float* x   = (const float*)d_in[0];
    const float* w1  = (const float*)d_in[1];
    const float* b1  = (const float*)d_in[2];
    const float* w2  = (const float*)d_in[3];
    const float* b2  = (const float*)d_in[4];
    const float* w3  = (const float*)d_in[5];
    const float* b3  = (const float*)d_in[6];
    const float* qw0 = (const float*)d_in[7];
    const float* kw0 = (const float*)d_in[8];
    const float* ww0 = (const float*)d_in[9];
    const float* qw1 = (const float*)d_in[10];
    const float* kw1 = (const float*)d_in[11];
    const float* ww1 = (const float*)d_in[12];
    const float* qw2 = (const float*)d_in[13];
    const float* kw2 = (const float*)d_in[14];
    const float* ww2 = (const float*)d_in[15];
    float* out = (float*)d_out;

    float* fb = (float*)d_ws;
    float* PA  = fb; fb += (size_t)B_ * 128 * D_;   // 1 MB
    float* PA2 = fb; fb += (size_t)B_ * 128 * D_;   // 1 MB
    float* MSD = fb; fb += 128;
    float* S1  = fb; fb += 64;
    __half* WP = (__half*)fb; fb += (size_t)B_ * 28 * T_ / 2;
    u16* ub = (u16*)fb;
    u16* Wh = ub; ub += (size_t)LDN * D_;      // 6.3 MB
    u16* Xh = ub; ub += (size_t)M_ * D_;       // 8 MB
    u16* Ph = ub; ub += (size_t)M_ * LDN;      // 25 MB

    prep<<<dim3(256 + LDN), 256, 0, stream>>>(x, PA, PA2, Xh,
                                              qw0, kw0, ww0, qw1, kw1, ww1,
                                              qw2, kw2, ww2, w1, Wh);
    stats2<<<dim3(B_), 1024, 0, stream>>>(PA, PA2, w1, MSD, S1);
    proj_gemm<<<dim3(M_ / 128, LDN / 128), 256, 0, stream>>>(Xh, Wh, Ph);
    selector2<<<dim3(M_ / 4), 256, 0, stream>>>(Ph, MSD, S1, b1, w2, b2, w3, b3, WP);
    score_kernel<<<dim3(T_ / 128, T_ / 128, B_), 256, 0, stream>>>(Ph, WP, out);
}

// Round 8
// 257.107 us; speedup vs baseline: 1.0494x; 1.0494x over previous
//
#include <hip/hip_runtime.h>
#include <hip/hip_fp16.h>
#include <cstdint>
#include <cstddef>
#include <math.h>

#define B_ 2
#define T_ 2048
#define D_ 1024
#define M_ (B_*T_)

// column layout of P (= row layout of W concat), all offsets multiples of 8
#define QO0 0
#define KO0 128
#define WO0 160
#define QO1 168
#define KO1 680
#define WO1 744
#define QO2 752
#define KO2 2800
#define WO2 2928
#define SELO 2944
#define LDN 3072

typedef float f32x16 __attribute__((ext_vector_type(16)));
typedef short bf16x8 __attribute__((ext_vector_type(8)));
typedef unsigned short u16;

__device__ __forceinline__ u16 f2bf(float f) {
    unsigned int u = __float_as_uint(f);
    unsigned int r = (u + 0x7fffu + ((u >> 16) & 1u)) >> 16;   // RNE
    return (u16)r;
}
__device__ __forceinline__ float bf2f(u16 b) {
    return __uint_as_float(((unsigned int)b) << 16);
}

// async global->LDS, 16B per lane, dest = wave-uniform base + lane*16
__device__ __forceinline__ void gload16(const void* g, void* l) {
    __builtin_amdgcn_global_load_lds(
        (const __attribute__((address_space(1))) unsigned int*)g,
        (__attribute__((address_space(3))) unsigned int*)l,
        16, 0, 0);
}

// Bank-conflict-free 16row x 32col u16 plane-slice staging with XOR swizzle.
// LDS slot s of row r holds logical 8-u16 chunk s ^ tkey(r), tkey(r) = (r&3)^((r>>2)&3).
__device__ __forceinline__ void stage_plane(const u16* src_base, int row_stride, int k0,
                                            int rg, int lane, u16* dst) {
    int rl  = lane >> 2;
    int row = rg * 16 + rl;
    int q   = (lane & 3) ^ (rl & 3) ^ ((rl >> 2) & 3);
    const u16* s = src_base + (size_t)row * row_stride + k0 + q * 8;
    gload16(s, dst + rg * 512);
}

// ---------------- merged: stats1 (64-row chunks, float4) | weight concat ----------------
__global__ void prep(const float* __restrict__ x, float* __restrict__ part,
                     float* __restrict__ part2, u16* __restrict__ Xh,
                     const float* __restrict__ qw0, const float* __restrict__ kw0,
                     const float* __restrict__ ww0, const float* __restrict__ qw1,
                     const float* __restrict__ kw1, const float* __restrict__ ww1,
                     const float* __restrict__ qw2, const float* __restrict__ kw2,
                     const float* __restrict__ ww2, const float* __restrict__ w1s,
                     u16* __restrict__ Wh) {
    int bid = blockIdx.x;
    if (bid < 64) {
        // stats part: 32 chunks x 64 rows per b -> stats2 reads only 256KB/block
        int d4 = threadIdx.x * 4;
        int tc = bid & 31;
        int b  = bid >> 5;
        size_t base = (size_t)b * T_ * D_ + (size_t)tc * 64 * D_ + d4;
        float4 s = make_float4(0.f, 0.f, 0.f, 0.f);
        float4 s2 = make_float4(0.f, 0.f, 0.f, 0.f);
#pragma unroll 8
        for (int t = 0; t < 64; ++t) {
            float4 v = *(const float4*)(x + base + (size_t)t * D_);
            s.x += v.x; s.y += v.y; s.z += v.z; s.w += v.w;
            s2.x += v.x * v.x; s2.y += v.y * v.y; s2.z += v.z * v.z; s2.w += v.w * v.w;
            ushort4 h;
            h.x = f2bf(v.x); h.y = f2bf(v.y); h.z = f2bf(v.z); h.w = f2bf(v.w);
            *(ushort4*)(Xh + base + (size_t)t * D_) = h;
        }
        *(float4*)(part  + (size_t)(b * 32 + tc) * D_ + d4) = s;
        *(float4*)(part2 + (size_t)(b * 32 + tc) * D_ + d4) = s2;
    } else {
        int row = bid - 64;
        int col = threadIdx.x * 4;
        const float* src = nullptr;
        if      (row < 128)  src = qw0 + (size_t)row * D_;
        else if (row < 160)  src = kw0 + (size_t)(row - 128) * D_;
        else if (row < 164)  src = ww0 + (size_t)(row - 160) * D_;
        else if (row < 168)  src = nullptr;
        else if (row < 680)  src = qw1 + (size_t)(row - 168) * D_;
        else if (row < 744)  src = kw1 + (size_t)(row - 680) * D_;
        else if (row < 752)  src = ww1 + (size_t)(row - 744) * D_;
        else if (row < 2800) src = qw2 + (size_t)(row - 752) * D_;
        else if (row < 2928) src = kw2 + (size_t)(row - 2800) * D_;
        else if (row < 2944) src = ww2 + (size_t)(row - 2928) * D_;
        else if (row < 3008) src = w1s + (size_t)(row - 2944) * D_;
        float4 v = src ? *(const float4*)(src + col) : make_float4(0.f, 0.f, 0.f, 0.f);
        ushort4 h;
        h.x = f2bf(v.x); h.y = f2bf(v.y); h.z = f2bf(v.z); h.w = f2bf(v.w);
        *(ushort4*)&Wh[(size_t)row * D_ + col] = h;
    }
}

// ---------------- pass 2: finalize mean+std, fold msd & s1 ----------------
__global__ void stats2(const float* __restrict__ part, const float* __restrict__ part2,
                       const float* __restrict__ w1,
                       float* __restrict__ msd, float* __restrict__ s1) {
    __shared__ float msL[1024];
    __shared__ float ps[64][17];
    __shared__ float pw[64][17];
    int b = blockIdx.x, tid = threadIdx.x;
    float s = 0.f, s2 = 0.f;
#pragma unroll 8
    for (int i = 0; i < 32; ++i) {
        s  += part [(b * 32 + i) * D_ + tid];
        s2 += part2[(b * 32 + i) * D_ + tid];
    }
    float mean = s / (float)T_;
    float var  = (s2 - (float)T_ * mean * mean) / (float)(T_ - 1);
    msL[tid] = mean + sqrtf(fmaxf(var, 0.f));
    __syncthreads();
    int j = tid >> 4, cc = tid & 15;
    float am = 0.f, aw = 0.f;
    const float* wr = w1 + (size_t)j * D_ + cc * 64;
    const float* mr = msL + cc * 64;
    for (int dd = 0; dd < 64; ++dd) { float w = wr[dd]; am += mr[dd] * w; aw += w; }
    ps[j][cc] = am; pw[j][cc] = aw;
    __syncthreads();
    if (tid < 64) {
        float sm = 0.f, sw = 0.f;
        for (int i = 0; i < 16; ++i) { sm += ps[tid][i]; sw += pw[tid][i]; }
        msd[b * 64 + tid] = sm;
        if (b == 0) s1[tid] = sw;
    }
}

// ---------------- projection GEMM, m97-style: BK=64 single-buffered ----------------
__global__ __launch_bounds__(256, 3) void proj_gemm(
    const u16* __restrict__ Xh, const u16* __restrict__ Wh, u16* __restrict__ Ph) {
    __shared__ u16 As[8192], Bs[8192];   // 128 rows x 64 cols (2 planes of 32)
    int tid = threadIdx.x;
    int wave = tid >> 6, lane = tid & 63;
    int bm = blockIdx.x * 128, bn = blockIdx.y * 128;
    int wt = wave >> 1, wn = wave & 1;
    int fm = lane & 31, hv = lane >> 5;
    int tkey = (fm & 3) ^ ((fm >> 2) & 3);
    f32x16 acc[2][2];
#pragma unroll
    for (int i = 0; i < 2; ++i)
#pragma unroll
        for (int j = 0; j < 2; ++j)
#pragma unroll
            for (int r = 0; r < 16; ++r) acc[i][j][r] = 0.f;

    const u16* xh = Xh + (size_t)bm * D_;
    const u16* wh = Wh + (size_t)bn * D_;

    for (int kc = 0; kc < 16; ++kc) {
        int k0 = kc * 64;
#pragma unroll
        for (int i = 0; i < 8; ++i) {
            int j = wave * 8 + i;
            int mat = j >> 4;
            int pl  = (j >> 3) & 1;
            int rg  = j & 7;
            stage_plane(mat ? wh : xh, D_, k0 + pl * 32, rg, lane,
                        (mat ? Bs : As) + pl * 4096);
        }
        __syncthreads();
#pragma unroll
        for (int ks = 0; ks < 4; ++ks) {
            int pl = ks >> 1;
            int slot8 = (((ks & 1) * 2 + hv) ^ tkey) * 8;
            bf16x8 a_h[2], b_h[2];
#pragma unroll
            for (int t = 0; t < 2; ++t) {
                a_h[t] = *(const bf16x8*)&As[pl * 4096 + (wt * 64 + t * 32 + fm) * 32 + slot8];
                b_h[t] = *(const bf16x8*)&Bs[pl * 4096 + (wn * 64 + t * 32 + fm) * 32 + slot8];
            }
#pragma unroll
            for (int ti = 0; ti < 2; ++ti)
#pragma unroll
                for (int tj = 0; tj < 2; ++tj)
                    acc[ti][tj] = __builtin_amdgcn_mfma_f32_32x32x16_bf16(a_h[ti], b_h[tj], acc[ti][tj], 0, 0, 0);
        }
        __syncthreads();
    }
#pragma unroll
    for (int ti = 0; ti < 2; ++ti)
#pragma unroll
        for (int tj = 0; tj < 2; ++tj)
#pragma unroll
            for (int r = 0; r < 16; ++r) {
                int row = bm + wt * 64 + ti * 32 + (r & 3) + 8 * (r >> 2) + 4 * hv;
                int col = bn + wn * 64 + tj * 32 + fm;
                Ph[(size_t)row * LDN + col] = f2bf(acc[ti][tj][r]);
            }
}

// ---------------- selector layers 2-3 + softmax + WP=w*prob (f16) ----------
__global__ void selector2(const u16* __restrict__ Ph,
                          const float* __restrict__ msd, const float* __restrict__ s1,
                          const float* __restrict__ b1, const float* __restrict__ w2,
                          const float* __restrict__ b2, const float* __restrict__ w3,
                          const float* __restrict__ b3, __half* __restrict__ WP) {
    __shared__ float h1s[4][64];
    __shared__ float h2s[4][64];
    __shared__ float lg[4][3];
    int tid = threadIdx.x;
    int slot = tid >> 6, j = tid & 63;
    int bt = blockIdx.x * 4 + slot;
    int b = bt >> 11, t = bt & 2047;
    size_t pidx = (size_t)bt * LDN + SELO + j;
    float v = bf2f(Ph[pidx])
            + msd[b * 64 + j] + 0.1f * ((float)t / (float)T_) * s1[j] + b1[j];
    h1s[slot][j] = fmaxf(v, 0.f);
    __syncthreads();
    float a2 = b2[j];
    {
        const float4* w2v = (const float4*)(w2 + (size_t)j * 64);
        const float4* h1v = (const float4*)h1s[slot];
#pragma unroll
        for (int d = 0; d < 16; ++d) {
            float4 wv = w2v[d], hv4 = h1v[d];
            a2 = fmaf(hv4.x, wv.x, a2);
            a2 = fmaf(hv4.y, wv.y, a2);
            a2 = fmaf(hv4.z, wv.z, a2);
            a2 = fmaf(hv4.w, wv.w, a2);
        }
    }
    h2s[slot][j] = fmaxf(a2, 0.f);
    __syncthreads();
    if (j < 3) {
        float a3 = b3[j];
        const float4* w3v = (const float4*)(w3 + (size_t)j * 64);
        const float4* h2v = (const float4*)h2s[slot];
#pragma unroll
        for (int d = 0; d < 16; ++d) {
            float4 wv = w3v[d], hv4 = h2v[d];
            a3 = fmaf(hv4.x, wv.x, a3);
            a3 = fmaf(hv4.y, wv.y, a3);
            a3 = fmaf(hv4.z, wv.z, a3);
            a3 = fmaf(hv4.w, wv.w, a3);
        }
        lg[slot][j] = a3;
    }
    __syncthreads();
    if (j < 28) {
        float m = fmaxf(lg[slot][0], fmaxf(lg[slot][1], lg[slot][2]));
        float e0 = expf(lg[slot][0] - m), e1 = expf(lg[slot][1] - m), e2 = expf(lg[slot][2] - m);
        float inv = 1.f / (e0 + e1 + e2);
        int wcol = (j < 4) ? (WO0 + j) : ((j < 12) ? (WO1 + j - 4) : (WO2 + j - 12));
        float p = ((j < 4) ? e0 : ((j < 12) ? e1 : e2)) * inv;
        float w = bf2f(Ph[(size_t)bt * LDN + wcol]);
        WP[(size_t)(b * 28 + j) * T_ + t] = __float2half(w * p);
    }
}

__device__ __forceinline__ int qcol_of(int c) {
    if (c < 2)  return QO0 + c * 64;
    if (c < 10) return QO1 + (c - 2) * 64;
    return QO2 + (c - 10) * 64;
}

// ---------------- fused relu-attention score kernel (R5 champion, 96.0us) ----------------
// block 128x128, 4 waves 64x64. Two-barrier counted-vmcnt phase schedule,
// ks-pipelined register double-buffer of fragments, nontemporal out stores.
__global__ __launch_bounds__(256, 2) void score_kernel(
    const u16* __restrict__ Ph, const __half* __restrict__ WP, float* __restrict__ out) {
    __shared__ u16 Qs[2][8192];    // dbuf: 2 planes x [128][32]
    __shared__ u16 Ks[4 * 4096];   // up to 4 planes x [128][32]
    __shared__ __half wpL[3584];   // [28][128]
    int tid = threadIdx.x;
    int wave = tid >> 6, lane = tid & 63;
    int wt = wave >> 1, wn = wave & 1;
    int fm = lane & 31, hv = lane >> 5;
    int tkey = (fm & 3) ^ ((fm >> 2) & 3);

    // XCD-aware swizzle: blocks sharing a Q-tile land on one XCD
    int n = blockIdx.z * 256 + blockIdx.y * 16 + blockIdx.x;
    int p = (n & 7) * 4 + (n >> 7);
    int xb = (n >> 3) & 15;
    int b = p >> 4, yb = p & 15;
    int t0 = yb * 128, s0 = xb * 128;

    const u16* Pq = Ph + (size_t)(b * T_ + t0) * LDN;
    const u16* Pk = Ph + (size_t)(b * T_ + s0) * LDN;

    auto stageQ = [&](int buf, int qcol) {
#pragma unroll
        for (int i = 0; i < 4; ++i) {
            int j = (wave << 2) + i;
            int pl = j >> 3, rg = j & 7;
            stage_plane(Pq, LDN, qcol + pl * 32, rg, lane, &Qs[buf][pl * 4096]);
        }
    };

    // prologue: K planes 0 (KO0), 1 (KO1), 2 (KO1+32) — 3 planes x 8 row-groups = 24 jobs
#pragma unroll
    for (int i = 0; i < 6; ++i) {
        int j = i * 4 + wave;                  // 0..23
        int pl = j >> 3, rg = j & 7;
        int col = (pl == 0) ? KO0 : ((pl == 1) ? KO1 : KO1 + 32);
        stage_plane(Pk, LDN, col, rg, lane, &Ks[pl * 4096]);
    }
    // wp slice: 28 rows of 128 halfs, 7 gload jobs
#pragma unroll
    for (int i = 0; i < 2; ++i) {
        int j = i * 4 + wave;
        if (j < 7) {
            const __half* src = WP + (size_t)(b * 28 + j * 4 + (lane >> 4)) * T_ + t0 + (lane & 15) * 8;
            gload16(src, (u16*)wpL + j * 512);
        }
    }
    stageQ(0, QO0);

    f32x16 outacc[2][2], dots[2][2], Z16;
#pragma unroll
    for (int r = 0; r < 16; ++r) Z16[r] = 0.f;
#pragma unroll
    for (int i = 0; i < 2; ++i)
#pragma unroll
        for (int j = 0; j < 2; ++j)
#pragma unroll
            for (int r = 0; r < 16; ++r) { outacc[i][j][r] = 0.f; dots[i][j][r] = 0.f; }

    // relu-weight epilogue for head g (dots -> outacc); b64 wpL loads
    auto epi = [&](int g) {
#pragma unroll
        for (int ti = 0; ti < 2; ++ti) {
            int rowbase = wt * 64 + ti * 32 + 4 * hv;
#pragma unroll
            for (int rq = 0; rq < 4; ++rq) {
                __half2 wpq[2];
                *(short4*)wpq = *(const short4*)&wpL[g * 128 + rowbase + rq * 8];
                float2 f01 = __half22float2(wpq[0]);
                float2 f23 = __half22float2(wpq[1]);
                float wv[4] = {f01.x, f01.y, f23.x, f23.y};
#pragma unroll
                for (int tj = 0; tj < 2; ++tj)
#pragma unroll
                    for (int r2 = 0; r2 < 4; ++r2) {
                        int r = rq * 4 + r2;
                        outacc[ti][tj][r] += fmaxf(dots[ti][tj][r], 0.f) * wv[r2];
                    }
            }
        }
    };

    // one phase: issue next stage, counted vmcnt, barrier A, ks-pipelined
    // reads+MFMA (setprio), epi, barrier B. Barrier B makes dbuf safe.
    auto runPhase = [&](int c, int kpA, int kpB, bool z0, bool midBreak,
                        int gMid, bool hasEnd, int gEnd) {
        if (c + 1 < 42) {
            stageQ((c + 1) & 1, qcol_of(c + 1));
            asm volatile("s_waitcnt vmcnt(4)" ::: "memory");
        } else {
            asm volatile("s_waitcnt vmcnt(0)" ::: "memory");
        }
        __builtin_amdgcn_s_barrier();            // A: stage(c) visible to all waves
        __builtin_amdgcn_sched_barrier(0);       // no LDS reads may float above A
        const u16* qb = Qs[c & 1];

        bf16x8 kf[2][2], qf[2][2];
        auto loadks = [&](int ks, int sl) {
            int kp = (ks < 2) ? kpA : kpB;
            int slot8 = (((ks & 1) * 2 + hv) ^ tkey) * 8;
#pragma unroll
            for (int tj = 0; tj < 2; ++tj)
                kf[sl][tj] = *(const bf16x8*)&Ks[kp * 4096 + (wn * 64 + tj * 32 + fm) * 32 + slot8];
#pragma unroll
            for (int ti = 0; ti < 2; ++ti)
                qf[sl][ti] = *(const bf16x8*)&qb[(ks >> 1) * 4096 + (wt * 64 + ti * 32 + fm) * 32 + slot8];
        };
        loadks(0, 0);
#pragma unroll
        for (int ks = 0; ks < 4; ++ks) {
            if (ks < 3) loadks(ks + 1, (ks + 1) & 1);
            bool zero = (ks == 0 && z0) || (ks == 2 && midBreak);
            int sl = ks & 1;
            __builtin_amdgcn_s_setprio(1);
#pragma unroll
            for (int ti = 0; ti < 2; ++ti)
#pragma unroll
                for (int tj = 0; tj < 2; ++tj)
                    dots[ti][tj] = __builtin_amdgcn_mfma_f32_32x32x16_bf16(
                        qf[sl][ti], kf[sl][tj], zero ? Z16 : dots[ti][tj], 0, 0, 0);
            __builtin_amdgcn_s_setprio(0);
            if (ks == 1 && midBreak) epi(gMid);
            if (ks == 3 && hasEnd)   epi(gEnd);
        }
        __builtin_amdgcn_sched_barrier(0);       // all reads retired before B
        __builtin_amdgcn_s_barrier();            // B: phase-c reads done everywhere
    };

    // cfg0: 2 phases, K plane 0, two d=32 heads per phase
#pragma unroll
    for (int c = 0; c < 2; ++c)
        runPhase(c, 0, 0, true, true, 2 * c, true, 2 * c + 1);
    // cfg1: 8 phases (one d=64 head each), K planes 1,2
    for (int h = 0; h < 8; ++h) {
        runPhase(2 + h, 1, 2, true, false, -1, true, 4 + h);
        if (h == 7) {
            // after barrier B of phase 9: all waves done with cfg0/cfg1 K planes.
            // Phase 10's vmcnt(4) retires these before its barrier A.
            for (int j = wave; j < 32; j += 4) {
                int pl = j >> 3, rg = j & 7;
                stage_plane(Pk, LDN, KO2 + pl * 32, rg, lane, &Ks[pl * 4096]);
            }
        }
    }
    // cfg2: 16 heads x 2 phases (d=128), K planes 0..3
    for (int h = 0; h < 16; ++h) {
        runPhase(10 + 2 * h, 0, 1, true, false, -1, false, -1);
        runPhase(11 + 2 * h, 2, 3, false, false, -1, true, 12 + h);
    }

#pragma unroll
    for (int ti = 0; ti < 2; ++ti)
#pragma unroll
        for (int tj = 0; tj < 2; ++tj)
#pragma unroll
            for (int r = 0; r < 16; ++r) {
                int trow = wt * 64 + ti * 32 + (r & 3) + 8 * (r >> 2) + 4 * hv;
                int scol = wn * 64 + tj * 32 + fm;
                __builtin_nontemporal_store(outacc[ti][tj][r],
                    &out[(size_t)(b * T_ + t0 + trow) * T_ + (s0 + scol)]);
            }
}

extern "C" void kernel_launch(void* const* d_in, const int* in_sizes, int n_in,
                              void* d_out, int out_size, void* d_ws, size_t ws_size,
                              hipStream_t stream) {
    const float* x   = (const float*)d_in[0];
    const float* w1  = (const float*)d_in[1];
    const float* b1  = (const float*)d_in[2];
    const float* w2  = (const float*)d_in[3];
    const float* b2  = (const float*)d_in[4];
    const float* w3  = (const float*)d_in[5];
    const float* b3  = (const float*)d_in[6];
    const float* qw0 = (const float*)d_in[7];
    const float* kw0 = (const float*)d_in[8];
    const float* ww0 = (const float*)d_in[9];
    const float* qw1 = (const float*)d_in[10];
    const float* kw1 = (const float*)d_in[11];
    const float* ww1 = (const float*)d_in[12];
    const float* qw2 = (const float*)d_in[13];
    const float* kw2 = (const float*)d_in[14];
    const float* ww2 = (const float*)d_in[15];
    float* out = (float*)d_out;

    float* fb = (float*)d_ws;
    float* PA  = fb; fb += (size_t)B_ * 32 * D_;
    float* PA2 = fb; fb += (size_t)B_ * 32 * D_;
    float* MSD = fb; fb += 128;
    float* S1  = fb; fb += 64;
    __half* WP = (__half*)fb; fb += (size_t)B_ * 28 * T_ / 2;
    u16* ub = (u16*)fb;
    u16* Wh = ub; ub += (size_t)LDN * D_;      // 6.3 MB
    u16* Xh = ub; ub += (size_t)M_ * D_;       // 8 MB
    u16* Ph = ub; ub += (size_t)M_ * LDN;      // 25 MB

    prep<<<dim3(64 + LDN), 256, 0, stream>>>(x, PA, PA2, Xh,
                                             qw0, kw0, ww0, qw1, kw1, ww1,
                                             qw2, kw2, ww2, w1, Wh);
    stats2<<<dim3(B_), 1024, 0, stream>>>(PA, PA2, w1, MSD, S1);
    proj_gemm<<<dim3(M_ / 128, LDN / 128), 256, 0, stream>>>(Xh, Wh, Ph);
    selector2<<<dim3(M_ / 4), 256, 0, stream>>>(Ph, MSD, S1, b1, w2, b2, w3, b3, WP);
    score_kernel<<<dim3(T_ / 128, T_ / 128, B_), 256, 0, stream>>>(Ph, WP, out);
}

// Round 9
// 255.096 us; speedup vs baseline: 1.0577x; 1.0079x over previous
//
#include <hip/hip_runtime.h>
#include <hip/hip_fp16.h>
#include <cstdint>
#include <cstddef>
#include <math.h>

#define B_ 2
#define T_ 2048
#define D_ 1024
#define M_ (B_*T_)

// column layout of P (= row layout of W concat), all offsets multiples of 8
#define QO0 0
#define KO0 128
#define WO0 160
#define QO1 168
#define KO1 680
#define WO1 744
#define QO2 752
#define KO2 2800
#define WO2 2928
#define SELO 2944
#define LDN 3072

typedef float f32x16 __attribute__((ext_vector_type(16)));
typedef short bf16x8 __attribute__((ext_vector_type(8)));
typedef unsigned short u16;

__device__ __forceinline__ u16 f2bf(float f) {
    unsigned int u = __float_as_uint(f);
    unsigned int r = (u + 0x7fffu + ((u >> 16) & 1u)) >> 16;   // RNE
    return (u16)r;
}
__device__ __forceinline__ float bf2f(u16 b) {
    return __uint_as_float(((unsigned int)b) << 16);
}

// async global->LDS, 16B per lane, dest = wave-uniform base + lane*16
__device__ __forceinline__ void gload16(const void* g, void* l) {
    __builtin_amdgcn_global_load_lds(
        (const __attribute__((address_space(1))) unsigned int*)g,
        (__attribute__((address_space(3))) unsigned int*)l,
        16, 0, 0);
}

// Bank-conflict-free 16row x 32col u16 plane-slice staging with XOR swizzle.
// LDS slot s of row r holds logical 8-u16 chunk s ^ tkey(r), tkey(r) = (r&3)^((r>>2)&3).
__device__ __forceinline__ void stage_plane(const u16* src_base, int row_stride, int k0,
                                            int rg, int lane, u16* dst) {
    int rl  = lane >> 2;
    int row = rg * 16 + rl;
    int q   = (lane & 3) ^ (rl & 3) ^ ((rl >> 2) & 3);
    const u16* s = src_base + (size_t)row * row_stride + k0 + q * 8;
    gload16(s, dst + rg * 512);
}

// ---------------- merged: stats1 (64-row chunks, float4) | weight concat ----------------
__global__ void prep(const float* __restrict__ x, float* __restrict__ part,
                     float* __restrict__ part2, u16* __restrict__ Xh,
                     const float* __restrict__ qw0, const float* __restrict__ kw0,
                     const float* __restrict__ ww0, const float* __restrict__ qw1,
                     const float* __restrict__ kw1, const float* __restrict__ ww1,
                     const float* __restrict__ qw2, const float* __restrict__ kw2,
                     const float* __restrict__ ww2, const float* __restrict__ w1s,
                     u16* __restrict__ Wh) {
    int bid = blockIdx.x;
    if (bid < 64) {
        // stats part: 32 chunks x 64 rows per b -> stats2 reads only 256KB/block
        int d4 = threadIdx.x * 4;
        int tc = bid & 31;
        int b  = bid >> 5;
        size_t base = (size_t)b * T_ * D_ + (size_t)tc * 64 * D_ + d4;
        float4 s = make_float4(0.f, 0.f, 0.f, 0.f);
        float4 s2 = make_float4(0.f, 0.f, 0.f, 0.f);
#pragma unroll 8
        for (int t = 0; t < 64; ++t) {
            float4 v = *(const float4*)(x + base + (size_t)t * D_);
            s.x += v.x; s.y += v.y; s.z += v.z; s.w += v.w;
            s2.x += v.x * v.x; s2.y += v.y * v.y; s2.z += v.z * v.z; s2.w += v.w * v.w;
            ushort4 h;
            h.x = f2bf(v.x); h.y = f2bf(v.y); h.z = f2bf(v.z); h.w = f2bf(v.w);
            *(ushort4*)(Xh + base + (size_t)t * D_) = h;
        }
        *(float4*)(part  + (size_t)(b * 32 + tc) * D_ + d4) = s;
        *(float4*)(part2 + (size_t)(b * 32 + tc) * D_ + d4) = s2;
    } else {
        int row = bid - 64;
        int col = threadIdx.x * 4;
        const float* src = nullptr;
        if      (row < 128)  src = qw0 + (size_t)row * D_;
        else if (row < 160)  src = kw0 + (size_t)(row - 128) * D_;
        else if (row < 164)  src = ww0 + (size_t)(row - 160) * D_;
        else if (row < 168)  src = nullptr;
        else if (row < 680)  src = qw1 + (size_t)(row - 168) * D_;
        else if (row < 744)  src = kw1 + (size_t)(row - 680) * D_;
        else if (row < 752)  src = ww1 + (size_t)(row - 744) * D_;
        else if (row < 2800) src = qw2 + (size_t)(row - 752) * D_;
        else if (row < 2928) src = kw2 + (size_t)(row - 2800) * D_;
        else if (row < 2944) src = ww2 + (size_t)(row - 2928) * D_;
        else if (row < 3008) src = w1s + (size_t)(row - 2944) * D_;
        float4 v = src ? *(const float4*)(src + col) : make_float4(0.f, 0.f, 0.f, 0.f);
        ushort4 h;
        h.x = f2bf(v.x); h.y = f2bf(v.y); h.z = f2bf(v.z); h.w = f2bf(v.w);
        *(ushort4*)&Wh[(size_t)row * D_ + col] = h;
    }
}

// ---------------- pass 2: finalize mean+std, fold msd & s1 ----------------
__global__ void stats2(const float* __restrict__ part, const float* __restrict__ part2,
                       const float* __restrict__ w1,
                       float* __restrict__ msd, float* __restrict__ s1) {
    __shared__ float msL[1024];
    __shared__ float ps[64][17];
    __shared__ float pw[64][17];
    int b = blockIdx.x, tid = threadIdx.x;
    float s = 0.f, s2 = 0.f;
#pragma unroll 8
    for (int i = 0; i < 32; ++i) {
        s  += part [(b * 32 + i) * D_ + tid];
        s2 += part2[(b * 32 + i) * D_ + tid];
    }
    float mean = s / (float)T_;
    float var  = (s2 - (float)T_ * mean * mean) / (float)(T_ - 1);
    msL[tid] = mean + sqrtf(fmaxf(var, 0.f));
    __syncthreads();
    int j = tid >> 4, cc = tid & 15;
    float am = 0.f, aw = 0.f;
    const float* wr = w1 + (size_t)j * D_ + cc * 64;
    const float* mr = msL + cc * 64;
    for (int dd = 0; dd < 64; ++dd) { float w = wr[dd]; am += mr[dd] * w; aw += w; }
    ps[j][cc] = am; pw[j][cc] = aw;
    __syncthreads();
    if (tid < 64) {
        float sm = 0.f, sw = 0.f;
        for (int i = 0; i < 16; ++i) { sm += ps[tid][i]; sw += pw[tid][i]; }
        msd[b * 64 + tid] = sm;
        if (b == 0) s1[tid] = sw;
    }
}

// ---------------- projection GEMM: 256x256 tile, 8 waves, dbuf LDS, counted vmcnt ----------------
// 192 blocks = 1/CU (LDS 128KB). Per K-step: stage next tile (8 jobs/wave),
// vmcnt(8), barrier A, 4 ks-steps x 8 MFMA (reg-prefetched ds_reads), barrier B.
// 32 MFMA per barrier-pair per wave (2x the 128^2 structure's amortization).
__global__ __launch_bounds__(512, 2) void proj_gemm(
    const u16* __restrict__ Xh, const u16* __restrict__ Wh, u16* __restrict__ Ph) {
    __shared__ u16 As[2][16384], Bs[2][16384];  // [buf][plane(2) x 256rows x 32cols]
    int tid = threadIdx.x;
    int wave = tid >> 6, lane = tid & 63;
    int wt = wave >> 2, wn = wave & 3;          // wave tile 128x64: rows wt*128, cols wn*64
    int fm = lane & 31, hv = lane >> 5;
    int tkey = (fm & 3) ^ ((fm >> 2) & 3);

    // XCD-chunked block swizzle: 192 = 8 XCDs x 24, consecutive p share the A row-panel
    int n = blockIdx.x;
    int p = (n & 7) * 24 + (n >> 3);
    int bm = (p / 12) * 256, bn = (p % 12) * 256;

    const u16* xh = Xh + (size_t)bm * D_;
    const u16* wh = Wh + (size_t)bn * D_;

    f32x16 acc[4][2];
#pragma unroll
    for (int i = 0; i < 4; ++i)
#pragma unroll
        for (int j = 0; j < 2; ++j)
#pragma unroll
            for (int r = 0; r < 16; ++r) acc[i][j][r] = 0.f;

    // stage one 256x64 A-tile + B-tile half (k0) into buf: 64 jobs, 8/wave
    auto stage = [&](int buf, int k0) {
#pragma unroll
        for (int i = 0; i < 8; ++i) {
            int j = wave * 8 + i;               // 0..63
            int mat = j >> 5;                   // 0=A, 1=B
            int jj  = j & 31;
            int pl  = jj >> 4, rg = jj & 15;    // plane, row-group (16 rows each)
            stage_plane(mat ? wh : xh, D_, k0 + pl * 32, rg, lane,
                        (mat ? Bs[buf] : As[buf]) + pl * 8192);
        }
    };

    stage(0, 0);
    for (int kc = 0; kc < 16; ++kc) {
        int buf = kc & 1;
        if (kc < 15) {
            stage(buf ^ 1, (kc + 1) * 64);
            asm volatile("s_waitcnt vmcnt(8)" ::: "memory");
        } else {
            asm volatile("s_waitcnt vmcnt(0)" ::: "memory");
        }
        __builtin_amdgcn_s_barrier();           // A: tile kc fully in LDS
        __builtin_amdgcn_sched_barrier(0);

        bf16x8 a[2][4], bq[2][2];
        auto loadks = [&](int ks, int sl) {
            int pl = ks >> 1;
            int slot8 = (((ks & 1) * 2 + hv) ^ tkey) * 8;
#pragma unroll
            for (int ti = 0; ti < 4; ++ti)
                a[sl][ti] = *(const bf16x8*)&As[buf][pl * 8192 + (wt * 128 + ti * 32 + fm) * 32 + slot8];
#pragma unroll
            for (int tj = 0; tj < 2; ++tj)
                bq[sl][tj] = *(const bf16x8*)&Bs[buf][pl * 8192 + (wn * 64 + tj * 32 + fm) * 32 + slot8];
        };
        loadks(0, 0);
#pragma unroll
        for (int ks = 0; ks < 4; ++ks) {
            if (ks < 3) loadks(ks + 1, (ks + 1) & 1);
            int sl = ks & 1;
            __builtin_amdgcn_s_setprio(1);
#pragma unroll
            for (int ti = 0; ti < 4; ++ti)
#pragma unroll
                for (int tj = 0; tj < 2; ++tj)
                    acc[ti][tj] = __builtin_amdgcn_mfma_f32_32x32x16_bf16(
                        a[sl][ti], bq[sl][tj], acc[ti][tj], 0, 0, 0);
            __builtin_amdgcn_s_setprio(0);
        }
        __builtin_amdgcn_sched_barrier(0);      // all tile-kc reads retired
        __builtin_amdgcn_s_barrier();           // B: safe to overwrite buf next iter
    }

#pragma unroll
    for (int ti = 0; ti < 4; ++ti)
#pragma unroll
        for (int tj = 0; tj < 2; ++tj)
#pragma unroll
            for (int r = 0; r < 16; ++r) {
                int row = bm + wt * 128 + ti * 32 + (r & 3) + 8 * (r >> 2) + 4 * hv;
                int col = bn + wn * 64 + tj * 32 + fm;
                Ph[(size_t)row * LDN + col] = f2bf(acc[ti][tj][r]);
            }
}

// ---------------- selector layers 2-3 + softmax + WP=w*prob (f16) ----------
__global__ void selector2(const u16* __restrict__ Ph,
                          const float* __restrict__ msd, const float* __restrict__ s1,
                          const float* __restrict__ b1, const float* __restrict__ w2,
                          const float* __restrict__ b2, const float* __restrict__ w3,
                          const float* __restrict__ b3, __half* __restrict__ WP) {
    __shared__ float h1s[4][64];
    __shared__ float h2s[4][64];
    __shared__ float lg[4][3];
    int tid = threadIdx.x;
    int slot = tid >> 6, j = tid & 63;
    int bt = blockIdx.x * 4 + slot;
    int b = bt >> 11, t = bt & 2047;
    size_t pidx = (size_t)bt * LDN + SELO + j;
    float v = bf2f(Ph[pidx])
            + msd[b * 64 + j] + 0.1f * ((float)t / (float)T_) * s1[j] + b1[j];
    h1s[slot][j] = fmaxf(v, 0.f);
    __syncthreads();
    float a2 = b2[j];
    {
        const float4* w2v = (const float4*)(w2 + (size_t)j * 64);
        const float4* h1v = (const float4*)h1s[slot];
#pragma unroll
        for (int d = 0; d < 16; ++d) {
            float4 wv = w2v[d], hv4 = h1v[d];
            a2 = fmaf(hv4.x, wv.x, a2);
            a2 = fmaf(hv4.y, wv.y, a2);
            a2 = fmaf(hv4.z, wv.z, a2);
            a2 = fmaf(hv4.w, wv.w, a2);
        }
    }
    h2s[slot][j] = fmaxf(a2, 0.f);
    __syncthreads();
    if (j < 3) {
        float a3 = b3[j];
        const float4* w3v = (const float4*)(w3 + (size_t)j * 64);
        const float4* h2v = (const float4*)h2s[slot];
#pragma unroll
        for (int d = 0; d < 16; ++d) {
            float4 wv = w3v[d], hv4 = h2v[d];
            a3 = fmaf(hv4.x, wv.x, a3);
            a3 = fmaf(hv4.y, wv.y, a3);
            a3 = fmaf(hv4.z, wv.z, a3);
            a3 = fmaf(hv4.w, wv.w, a3);
        }
        lg[slot][j] = a3;
    }
    __syncthreads();
    if (j < 28) {
        float m = fmaxf(lg[slot][0], fmaxf(lg[slot][1], lg[slot][2]));
        float e0 = expf(lg[slot][0] - m), e1 = expf(lg[slot][1] - m), e2 = expf(lg[slot][2] - m);
        float inv = 1.f / (e0 + e1 + e2);
        int wcol = (j < 4) ? (WO0 + j) : ((j < 12) ? (WO1 + j - 4) : (WO2 + j - 12));
        float p = ((j < 4) ? e0 : ((j < 12) ? e1 : e2)) * inv;
        float w = bf2f(Ph[(size_t)bt * LDN + wcol]);
        WP[(size_t)(b * 28 + j) * T_ + t] = __float2half(w * p);
    }
}

__device__ __forceinline__ int qcol_of(int c) {
    if (c < 2)  return QO0 + c * 64;
    if (c < 10) return QO1 + (c - 2) * 64;
    return QO2 + (c - 10) * 64;
}

// ---------------- fused relu-attention score kernel (R5 champion, 96.0us) ----------------
// block 128x128, 4 waves 64x64. Two-barrier counted-vmcnt phase schedule,
// ks-pipelined register double-buffer of fragments, nontemporal out stores.
__global__ __launch_bounds__(256, 2) void score_kernel(
    const u16* __restrict__ Ph, const __half* __restrict__ WP, float* __restrict__ out) {
    __shared__ u16 Qs[2][8192];    // dbuf: 2 planes x [128][32]
    __shared__ u16 Ks[4 * 4096];   // up to 4 planes x [128][32]
    __shared__ __half wpL[3584];   // [28][128]
    int tid = threadIdx.x;
    int wave = tid >> 6, lane = tid & 63;
    int wt = wave >> 1, wn = wave & 1;
    int fm = lane & 31, hv = lane >> 5;
    int tkey = (fm & 3) ^ ((fm >> 2) & 3);

    // XCD-aware swizzle: blocks sharing a Q-tile land on one XCD
    int n = blockIdx.z * 256 + blockIdx.y * 16 + blockIdx.x;
    int p = (n & 7) * 4 + (n >> 7);
    int xb = (n >> 3) & 15;
    int b = p >> 4, yb = p & 15;
    int t0 = yb * 128, s0 = xb * 128;

    const u16* Pq = Ph + (size_t)(b * T_ + t0) * LDN;
    const u16* Pk = Ph + (size_t)(b * T_ + s0) * LDN;

    auto stageQ = [&](int buf, int qcol) {
#pragma unroll
        for (int i = 0; i < 4; ++i) {
            int j = (wave << 2) + i;
            int pl = j >> 3, rg = j & 7;
            stage_plane(Pq, LDN, qcol + pl * 32, rg, lane, &Qs[buf][pl * 4096]);
        }
    };

    // prologue: K planes 0 (KO0), 1 (KO1), 2 (KO1+32) — 3 planes x 8 row-groups = 24 jobs
#pragma unroll
    for (int i = 0; i < 6; ++i) {
        int j = i * 4 + wave;                  // 0..23
        int pl = j >> 3, rg = j & 7;
        int col = (pl == 0) ? KO0 : ((pl == 1) ? KO1 : KO1 + 32);
        stage_plane(Pk, LDN, col, rg, lane, &Ks[pl * 4096]);
    }
    // wp slice: 28 rows of 128 halfs, 7 gload jobs
#pragma unroll
    for (int i = 0; i < 2; ++i) {
        int j = i * 4 + wave;
        if (j < 7) {
            const __half* src = WP + (size_t)(b * 28 + j * 4 + (lane >> 4)) * T_ + t0 + (lane & 15) * 8;
            gload16(src, (u16*)wpL + j * 512);
        }
    }
    stageQ(0, QO0);

    f32x16 outacc[2][2], dots[2][2], Z16;
#pragma unroll
    for (int r = 0; r < 16; ++r) Z16[r] = 0.f;
#pragma unroll
    for (int i = 0; i < 2; ++i)
#pragma unroll
        for (int j = 0; j < 2; ++j)
#pragma unroll
            for (int r = 0; r < 16; ++r) { outacc[i][j][r] = 0.f; dots[i][j][r] = 0.f; }

    // relu-weight epilogue for head g (dots -> outacc); b64 wpL loads
    auto epi = [&](int g) {
#pragma unroll
        for (int ti = 0; ti < 2; ++ti) {
            int rowbase = wt * 64 + ti * 32 + 4 * hv;
#pragma unroll
            for (int rq = 0; rq < 4; ++rq) {
                __half2 wpq[2];
                *(short4*)wpq = *(const short4*)&wpL[g * 128 + rowbase + rq * 8];
                float2 f01 = __half22float2(wpq[0]);
                float2 f23 = __half22float2(wpq[1]);
                float wv[4] = {f01.x, f01.y, f23.x, f23.y};
#pragma unroll
                for (int tj = 0; tj < 2; ++tj)
#pragma unroll
                    for (int r2 = 0; r2 < 4; ++r2) {
                        int r = rq * 4 + r2;
                        outacc[ti][tj][r] += fmaxf(dots[ti][tj][r], 0.f) * wv[r2];
                    }
            }
        }
    };

    // one phase: issue next stage, counted vmcnt, barrier A, ks-pipelined
    // reads+MFMA (setprio), epi, barrier B. Barrier B makes dbuf safe.
    auto runPhase = [&](int c, int kpA, int kpB, bool z0, bool midBreak,
                        int gMid, bool hasEnd, int gEnd) {
        if (c + 1 < 42) {
            stageQ((c + 1) & 1, qcol_of(c + 1));
            asm volatile("s_waitcnt vmcnt(4)" ::: "memory");
        } else {
            asm volatile("s_waitcnt vmcnt(0)" ::: "memory");
        }
        __builtin_amdgcn_s_barrier();            // A: stage(c) visible to all waves
        __builtin_amdgcn_sched_barrier(0);       // no LDS reads may float above A
        const u16* qb = Qs[c & 1];

        bf16x8 kf[2][2], qf[2][2];
        auto loadks = [&](int ks, int sl) {
            int kp = (ks < 2) ? kpA : kpB;
            int slot8 = (((ks & 1) * 2 + hv) ^ tkey) * 8;
#pragma unroll
            for (int tj = 0; tj < 2; ++tj)
                kf[sl][tj] = *(const bf16x8*)&Ks[kp * 4096 + (wn * 64 + tj * 32 + fm) * 32 + slot8];
#pragma unroll
            for (int ti = 0; ti < 2; ++ti)
                qf[sl][ti] = *(const bf16x8*)&qb[(ks >> 1) * 4096 + (wt * 64 + ti * 32 + fm) * 32 + slot8];
        };
        loadks(0, 0);
#pragma unroll
        for (int ks = 0; ks < 4; ++ks) {
            if (ks < 3) loadks(ks + 1, (ks + 1) & 1);
            bool zero = (ks == 0 && z0) || (ks == 2 && midBreak);
            int sl = ks & 1;
            __builtin_amdgcn_s_setprio(1);
#pragma unroll
            for (int ti = 0; ti < 2; ++ti)
#pragma unroll
                for (int tj = 0; tj < 2; ++tj)
                    dots[ti][tj] = __builtin_amdgcn_mfma_f32_32x32x16_bf16(
                        qf[sl][ti], kf[sl][tj], zero ? Z16 : dots[ti][tj], 0, 0, 0);
            __builtin_amdgcn_s_setprio(0);
            if (ks == 1 && midBreak) epi(gMid);
            if (ks == 3 && hasEnd)   epi(gEnd);
        }
        __builtin_amdgcn_sched_barrier(0);       // all reads retired before B
        __builtin_amdgcn_s_barrier();            // B: phase-c reads done everywhere
    };

    // cfg0: 2 phases, K plane 0, two d=32 heads per phase
#pragma unroll
    for (int c = 0; c < 2; ++c)
        runPhase(c, 0, 0, true, true, 2 * c, true, 2 * c + 1);
    // cfg1: 8 phases (one d=64 head each), K planes 1,2
    for (int h = 0; h < 8; ++h) {
        runPhase(2 + h, 1, 2, true, false, -1, true, 4 + h);
        if (h == 7) {
            // after barrier B of phase 9: all waves done with cfg0/cfg1 K planes.
            // Phase 10's vmcnt(4) retires these before its barrier A.
            for (int j = wave; j < 32; j += 4) {
                int pl = j >> 3, rg = j & 7;
                stage_plane(Pk, LDN, KO2 + pl * 32, rg, lane, &Ks[pl * 4096]);
            }
        }
    }
    // cfg2: 16 heads x 2 phases (d=128), K planes 0..3
    for (int h = 0; h < 16; ++h) {
        runPhase(10 + 2 * h, 0, 1, true, false, -1, false, -1);
        runPhase(11 + 2 * h, 2, 3, false, false, -1, true, 12 + h);
    }

#pragma unroll
    for (int ti = 0; ti < 2; ++ti)
#pragma unroll
        for (int tj = 0; tj < 2; ++tj)
#pragma unroll
            for (int r = 0; r < 16; ++r) {
                int trow = wt * 64 + ti * 32 + (r & 3) + 8 * (r >> 2) + 4 * hv;
                int scol = wn * 64 + tj * 32 + fm;
                __builtin_nontemporal_store(outacc[ti][tj][r],
                    &out[(size_t)(b * T_ + t0 + trow) * T_ + (s0 + scol)]);
            }
}

extern "C" void kernel_launch(void* const* d_in, const int* in_sizes, int n_in,
                              void* d_out, int out_size, void* d_ws, size_t ws_size,
                              hipStream_t stream) {
    const float* x   = (const float*)d_in[0];
    const float* w1  = (const float*)d_in[1];
    const float* b1  = (const float*)d_in[2];
    const float* w2  = (const float*)d_in[3];
    const float* b2  = (const float*)d_in[4];
    const float* w3  = (const float*)d_in[5];
    const float* b3  = (const float*)d_in[6];
    const float* qw0 = (const float*)d_in[7];
    const float* kw0 = (const float*)d_in[8];
    const float* ww0 = (const float*)d_in[9];
    const float* qw1 = (const float*)d_in[10];
    const float* kw1 = (const float*)d_in[11];
    const float* ww1 = (const float*)d_in[12];
    const float* qw2 = (const float*)d_in[13];
    const float* kw2 = (const float*)d_in[14];
    const float* ww2 = (const float*)d_in[15];
    float* out = (float*)d_out;

    float* fb = (float*)d_ws;
    float* PA  = fb; fb += (size_t)B_ * 32 * D_;
    float* PA2 = fb; fb += (size_t)B_ * 32 * D_;
    float* MSD = fb; fb += 128;
    float* S1  = fb; fb += 64;
    __half* WP = (__half*)fb; fb += (size_t)B_ * 28 * T_ / 2;
    u16* ub = (u16*)fb;
    u16* Wh = ub; ub += (size_t)LDN * D_;      // 6.3 MB
    u16* Xh = ub; ub += (size_t)M_ * D_;       // 8 MB
    u16* Ph = ub; ub += (size_t)M_ * LDN;      // 25 MB

    prep<<<dim3(64 + LDN), 256, 0, stream>>>(x, PA, PA2, Xh,
                                             qw0, kw0, ww0, qw1, kw1, ww1,
                                             qw2, kw2, ww2, w1, Wh);
    stats2<<<dim3(B_), 1024, 0, stream>>>(PA, PA2, w1, MSD, S1);
    proj_gemm<<<dim3(192), 512, 0, stream>>>(Xh, Wh, Ph);
    selector2<<<dim3(M_ / 4), 256, 0, stream>>>(Ph, MSD, S1, b1, w2, b2, w3, b3, WP);
    score_kernel<<<dim3(T_ / 128, T_ / 128, B_), 256, 0, stream>>>(Ph, WP, out);
}